// Round 16
// baseline (87.337 us; speedup 1.0000x reference)
//
#include <hip/hip_runtime.h>

// GCN 2-layer for MI355X — two-level counting sort to per-node CSR, then
// atomic-free register-reduction aggregation.
// r16 micro-opts: k_part writes records DIRECTLY to its private packed
// segment (no LDS stage round-trip; scatter confined to one block's 25KB
// window -> single-XCD L2 write-combining); k_csr caches raw records in
// registers between count and scatter; aggs load int2 seg instead of
// separate nstart/nend.
//
// record: src (bits 0..16) | local_dst (bits 17..24), NPB=256

#define NPB    256
#define NBSH   8
#define NPART  512      // partition blocks
#define PBS    512      // k_part threads
#define EPT    13       // edges/thread in k_part (epb=6250 <= 6656)
#define CAP    9728     // per-bucket capacity (mean 8184, sd ~90; +17 sd)
#define CBS    1024     // k_csr threads
#define CITER  10       // ceil(CAP/CBS)
#define ABS    256      // agg threads
#define LPN    8        // lanes per node in agg

// Block-wide exclusive scan via wave shuffles. NW = waves/block.
template <int NW>
__device__ __forceinline__ int block_exscan(int v, int t, int* wsum) {
    int lane = t & 63, wid = t >> 6;
    int inc = v;
#pragma unroll
    for (int off = 1; off < 64; off <<= 1) {
        int u = __shfl_up(inc, off);
        if (lane >= off) inc += u;
    }
    if (lane == 63) wsum[wid] = inc;
    __syncthreads();
    if (wid == 0) {
        int w = (lane < NW) ? wsum[lane] : 0;
#pragma unroll
        for (int off = 1; off < NW; off <<= 1) {
            int u = __shfl_up(w, off);
            if (lane >= off) w += u;
        }
        if (lane < NW) wsum[lane] = w;
    }
    __syncthreads();
    return inc - v + (wid ? wsum[wid - 1] : 0);
}

// ---- level 1: block-major bucket sort, direct global scatter ----
__global__ __launch_bounds__(PBS) void k_part(
    const int* __restrict__ src, const int* __restrict__ dst,
    int E, int epb, int nbuck,
    int* __restrict__ offT, unsigned* __restrict__ packed)
{
    __shared__ int s_scan[PBS];
    __shared__ int wsum[PBS / 64];
    const int b = blockIdx.x, t = threadIdx.x;
    const int lo = b * epb;
    int blockEdges = min(epb, E - lo); if (blockEdges < 0) blockEdges = 0;

    int sreg[EPT], dreg[EPT];
    s_scan[t] = 0;
    __syncthreads();
#pragma unroll
    for (int it = 0; it < EPT; ++it) {
        int idx = it * PBS + t;
        dreg[it] = -1;
        if (idx < blockEdges) {
            dreg[it] = dst[lo + idx];
            sreg[it] = src[lo + idx];
            atomicAdd(&s_scan[dreg[it] >> NBSH], 1);
        }
    }
    __syncthreads();
    int v = s_scan[t];
    __syncthreads();
    int excl = block_exscan<PBS / 64>(v, t, wsum);
    s_scan[t] = excl;                          // reuse as cursors
    if (t < nbuck) offT[(size_t)b * nbuck + t] = excl;
    __syncthreads();
    unsigned* pb = packed + (size_t)lo;
#pragma unroll
    for (int it = 0; it < EPT; ++it)
        if (dreg[it] >= 0) {
            int d = dreg[it];
            int pos = atomicAdd(&s_scan[d >> NBSH], 1);
            pb[pos] = (unsigned)sreg[it] | ((unsigned)(d & (NPB - 1)) << 17);
        }
}

// ---- level 2: per-bucket node-level sort -> CSR + deg/dis/p1 fused ----
__global__ __launch_bounds__(CBS) void k_csr(
    const unsigned* __restrict__ packed, const int* __restrict__ offT,
    const float* __restrict__ x,
    int E, int epb, int nbuck, int n,
    unsigned* __restrict__ sorted, int2* __restrict__ seg,
    float* __restrict__ dis, float* __restrict__ p1)
{
    __shared__ unsigned raw[CAP];
    __shared__ int offs[NPART], fbase[NPART];
    __shared__ int cnt[NPB], cur[NPB];
    __shared__ int wsum[CBS / 64];
    __shared__ int s_bsize;
    const int k = blockIdx.x, t = threadIdx.x;

    int o = 0, myflen = 0;
    if (t < NPART) {
        o = offT[(size_t)t * nbuck + k];
        int e = (k + 1 < nbuck) ? offT[(size_t)t * nbuck + k + 1]
                                : max(0, min(epb, E - t * epb));
        myflen = e - o;
        offs[t] = o;
    }
    if (t < NPB) cnt[t] = 0;
    __syncthreads();
    int fexcl = block_exscan<CBS / 64>(myflen, t, wsum);
    if (t < NPART) fbase[t] = fexcl;
    if (t == NPART - 1) s_bsize = min(fexcl + myflen, CAP);
    __syncthreads();
    const int bsize = s_bsize;
    // gather fragments into raw[]: 16 contiguous lanes per fragment (64 B)
    for (int fb = 0; fb < NPART; fb += (CBS >> 4)) {
        int f = fb + (t >> 4);
        const unsigned* pp = packed + (size_t)f * epb + offs[f];
        int base = fbase[f];
        int len  = ((f + 1 < NPART) ? fbase[f + 1] : bsize) - base;
        for (int i = (t & 15); i < len; i += 16) {
            int p = base + i;
            if (p < CAP) raw[p] = pp[i];
        }
    }
    __syncthreads();
    // node-level count; cache records in registers for the scatter
    unsigned rr[CITER];
#pragma unroll
    for (int j = 0; j < CITER; ++j) {
        int i = j * CBS + t;
        rr[j] = 0xFFFFFFFFu;
        if (i < bsize) {
            rr[j] = raw[i];
            atomicAdd(&cnt[rr[j] >> 17], 1);
        }
    }
    __syncthreads();
    int myc = (t < NPB) ? cnt[t] : 0;
    __syncthreads();
    int cexcl = block_exscan<CBS / 64>(myc, t, wsum);
    if (t < NPB) {
        cur[t] = cexcl;                        // cursor for scatter
        int d = k * NPB + t;
        if (d < n) {
            int st = k * CAP + cexcl;
            seg[d] = make_int2(st, min(st + myc, (k + 1) * CAP));
            float r = rsqrtf((float)(myc + 1)); // +1 self-loop
            dis[d] = r;
            p1[d]  = x[d] * r;
        }
    }
    __syncthreads();
    // scatter into node-sorted order (from registers)
    unsigned* sb = sorted + (size_t)k * CAP;
#pragma unroll
    for (int j = 0; j < CITER; ++j)
        if (rr[j] != 0xFFFFFFFFu) {
            int pos = atomicAdd(&cur[rr[j] >> 17], 1);
            sb[pos] = rr[j];
        }
}

// ---- layer 1: atomic-free segment reduce + fused MLP -> p2 ----
__global__ __launch_bounds__(ABS) void k_agg1(
    const unsigned* __restrict__ sorted, const int2* __restrict__ seg,
    const float* __restrict__ dis, const float* __restrict__ p1,
    const float* __restrict__ W1, const float* __restrict__ b1,
    const float* __restrict__ W2, int n, float2* __restrict__ p2)
{
    int gid = blockIdx.x * ABS + threadIdx.x;
    int d = gid >> 3, lane = gid & (LPN - 1);
    if (d >= n) return;
    int2 se = seg[d];
    int s0 = se.x, e0 = se.y;
    float acc = 0.f;
    int i = s0 + lane;
    for (; i + 3 * LPN < e0; i += 4 * LPN) {   // 4 independent gathers in flight
        acc += p1[sorted[i] & 0x1FFFFu] + p1[sorted[i + LPN] & 0x1FFFFu]
             + p1[sorted[i + 2 * LPN] & 0x1FFFFu]
             + p1[sorted[i + 3 * LPN] & 0x1FFFFu];
    }
    for (; i < e0; i += LPN) acc += p1[sorted[i] & 0x1FFFFu];
    acc += __shfl_xor(acc, 1);
    acc += __shfl_xor(acc, 2);
    acc += __shfl_xor(acc, 4);
    if (lane == 0) {
        float r   = dis[d];
        float agg = r * (acc + p1[d]);          // + self-loop
        float c0 = 0.f, c1 = 0.f;
#pragma unroll
        for (int j = 0; j < 16; ++j) {
            float h = fmaxf(fmaf(agg, W1[j], b1[j]), 0.f);
            c0 = fmaf(h, W2[2 * j],     c0);
            c1 = fmaf(h, W2[2 * j + 1], c1);
        }
        p2[d] = make_float2(c0 * r, c1 * r);    // prescaled by dis[src]
    }
}

// ---- layer 2: atomic-free segment reduce + fused log-softmax -> out ----
__global__ __launch_bounds__(ABS) void k_agg2(
    const unsigned* __restrict__ sorted, const int2* __restrict__ seg,
    const float* __restrict__ dis, const float2* __restrict__ p2,
    const float* __restrict__ b2, int n, float2* __restrict__ out)
{
    int gid = blockIdx.x * ABS + threadIdx.x;
    int d = gid >> 3, lane = gid & (LPN - 1);
    if (d >= n) return;
    int2 se = seg[d];
    int s0 = se.x, e0 = se.y;
    float c0 = 0.f, c1 = 0.f;
    int i = s0 + lane;
    for (; i + 3 * LPN < e0; i += 4 * LPN) {   // 4 gathers in flight
        float2 v0 = p2[sorted[i]           & 0x1FFFFu];
        float2 v1 = p2[sorted[i + LPN]     & 0x1FFFFu];
        float2 v2 = p2[sorted[i + 2 * LPN] & 0x1FFFFu];
        float2 v3 = p2[sorted[i + 3 * LPN] & 0x1FFFFu];
        c0 += v0.x + v1.x + v2.x + v3.x;
        c1 += v0.y + v1.y + v2.y + v3.y;
    }
    for (; i < e0; i += LPN) {
        float2 v = p2[sorted[i] & 0x1FFFFu];
        c0 += v.x; c1 += v.y;
    }
    c0 += __shfl_xor(c0, 1); c0 += __shfl_xor(c0, 2); c0 += __shfl_xor(c0, 4);
    c1 += __shfl_xor(c1, 1); c1 += __shfl_xor(c1, 2); c1 += __shfl_xor(c1, 4);
    if (lane == 0) {
        float r = dis[d];
        float2 self = p2[d];
        float o0 = r * (c0 + self.x) + b2[0];
        float o1 = r * (c1 + self.y) + b2[1];
        float m  = fmaxf(o0, o1);
        float ls = m + logf(expf(o0 - m) + expf(o1 - m));
        out[d] = make_float2(o0 - ls, o1 - ls);
    }
}

extern "C" void kernel_launch(void* const* d_in, const int* in_sizes, int n_in,
                              void* d_out, int out_size, void* d_ws, size_t ws_size,
                              hipStream_t stream) {
    const float* x  = (const float*)d_in[0];
    const int*   ei = (const int*)d_in[1];     // int32 [2, E]
    const float* W1 = (const float*)d_in[2];
    const float* b1 = (const float*)d_in[3];
    const float* W2 = (const float*)d_in[4];
    const float* b2 = (const float*)d_in[5];

    const int n = in_sizes[0];                 // 100000
    const int E = in_sizes[1] / 2;             // 3200000
    const int* src = ei;
    const int* dst = ei + E;

    const int nbuck = (n + NPB - 1) >> NBSH;   // 391
    const int epb   = (E + NPART - 1) / NPART; // 6250

    char* ws = (char*)d_ws;
    size_t off = 0;
    auto take = [&](size_t bytes) { char* p = ws + off; off += (bytes + 7) & ~(size_t)7; return p; };
    int*      offT   = (int*)take((size_t)NPART * nbuck * 4);     // 0.8 MB
    unsigned* packed = (unsigned*)take((size_t)E * 4);            // 12.8 MB
    unsigned* sorted = (unsigned*)take((size_t)nbuck * CAP * 4);  // 15.2 MB
    int2*     seg    = (int2*)take((size_t)n * 8);
    float*    dis    = (float*)take((size_t)n * 4);
    float*    p1     = (float*)take((size_t)n * 4);
    float2*   p2     = (float2*)take((size_t)n * 8);

    const int gridAgg = ((size_t)n * LPN + ABS - 1) / ABS;        // 3125

    k_part<<<NPART, PBS, 0, stream>>>(src, dst, E, epb, nbuck, offT, packed);
    k_csr <<<nbuck, CBS, 0, stream>>>(packed, offT, x, E, epb, nbuck, n,
                                      sorted, seg, dis, p1);
    k_agg1<<<gridAgg, ABS, 0, stream>>>(sorted, seg, dis, p1,
                                        W1, b1, W2, n, p2);
    k_agg2<<<gridAgg, ABS, 0, stream>>>(sorted, seg, dis, p2,
                                        b2, n, (float2*)d_out);
}

// Round 17
// 76.146 us; speedup vs baseline: 1.1470x; 1.1470x over previous
//
#include <hip/hip_runtime.h>

// GCN 2-layer for MI355X — two-level counting sort to per-node CSR, then
// atomic-free register-reduction aggregation.
// r17 = r15's k_part (LDS stage + coalesced flush; r16 proved direct global
// scatter costs +11us even L2-local) + r16's csr register-cache and int2 seg.
//
// record: src (bits 0..16) | local_dst (bits 17..24), NPB=256

#define NPB    256
#define NBSH   8
#define NPART  512      // partition blocks
#define PBS    1024     // k_part threads
#define EPT    7        // edges/thread in k_part (epb=6250 <= 7168)
#define CAP    9728     // per-bucket capacity (mean 8184, sd ~90; +17 sd)
#define CBS    1024     // k_csr threads
#define CITER  10       // ceil(CAP/CBS)
#define ABS    256      // agg threads
#define LPN    8        // lanes per node in agg

// Block-wide exclusive scan via wave shuffles. NW = waves/block.
template <int NW>
__device__ __forceinline__ int block_exscan(int v, int t, int* wsum) {
    int lane = t & 63, wid = t >> 6;
    int inc = v;
#pragma unroll
    for (int off = 1; off < 64; off <<= 1) {
        int u = __shfl_up(inc, off);
        if (lane >= off) inc += u;
    }
    if (lane == 63) wsum[wid] = inc;
    __syncthreads();
    if (wid == 0) {
        int w = (lane < NW) ? wsum[lane] : 0;
#pragma unroll
        for (int off = 1; off < NW; off <<= 1) {
            int u = __shfl_up(w, off);
            if (lane >= off) w += u;
        }
        if (lane < NW) wsum[lane] = w;
    }
    __syncthreads();
    return inc - v + (wid ? wsum[wid - 1] : 0);
}

// ---- level 1: block-major bucket sort (LDS stage + coalesced flush) ----
__global__ __launch_bounds__(PBS) void k_part(
    const int* __restrict__ src, const int* __restrict__ dst,
    int E, int epb, int nbuck,
    int* __restrict__ offT, unsigned* __restrict__ packed)
{
    __shared__ int s_scan[PBS];
    __shared__ unsigned stage[PBS * EPT];
    __shared__ int wsum[PBS / 64];
    const int b = blockIdx.x, t = threadIdx.x;
    const int lo = b * epb;
    int blockEdges = min(epb, E - lo); if (blockEdges < 0) blockEdges = 0;

    unsigned rec[EPT]; int bkt[EPT];
    s_scan[t] = 0;
    __syncthreads();
#pragma unroll
    for (int it = 0; it < EPT; ++it) {
        int idx = it * PBS + t;
        bkt[it] = -1; rec[it] = 0;
        if (idx < blockEdges) {
            int d = dst[lo + idx], s = src[lo + idx];
            rec[it] = (unsigned)s | ((unsigned)(d & (NPB - 1)) << 17);
            bkt[it] = d >> NBSH;
            atomicAdd(&s_scan[bkt[it]], 1);
        }
    }
    __syncthreads();
    int v = s_scan[t];
    __syncthreads();
    int excl = block_exscan<PBS / 64>(v, t, wsum);
    s_scan[t] = excl;                          // reuse as cursors
    if (t < nbuck) offT[(size_t)b * nbuck + t] = excl;
    __syncthreads();
#pragma unroll
    for (int it = 0; it < EPT; ++it)
        if (bkt[it] >= 0) {
            int pos = atomicAdd(&s_scan[bkt[it]], 1);
            stage[pos] = rec[it];
        }
    __syncthreads();
    for (int i = t; i < blockEdges; i += PBS)
        packed[(size_t)lo + i] = stage[i];
}

// ---- level 2: per-bucket node-level sort -> CSR + deg/dis/p1 fused ----
__global__ __launch_bounds__(CBS) void k_csr(
    const unsigned* __restrict__ packed, const int* __restrict__ offT,
    const float* __restrict__ x,
    int E, int epb, int nbuck, int n,
    unsigned* __restrict__ sorted, int2* __restrict__ seg,
    float* __restrict__ dis, float* __restrict__ p1)
{
    __shared__ unsigned raw[CAP];
    __shared__ int offs[NPART], fbase[NPART];
    __shared__ int cnt[NPB], cur[NPB];
    __shared__ int wsum[CBS / 64];
    __shared__ int s_bsize;
    const int k = blockIdx.x, t = threadIdx.x;

    int o = 0, myflen = 0;
    if (t < NPART) {
        o = offT[(size_t)t * nbuck + k];
        int e = (k + 1 < nbuck) ? offT[(size_t)t * nbuck + k + 1]
                                : max(0, min(epb, E - t * epb));
        myflen = e - o;
        offs[t] = o;
    }
    if (t < NPB) cnt[t] = 0;
    __syncthreads();
    int fexcl = block_exscan<CBS / 64>(myflen, t, wsum);
    if (t < NPART) fbase[t] = fexcl;
    if (t == NPART - 1) s_bsize = min(fexcl + myflen, CAP);
    __syncthreads();
    const int bsize = s_bsize;
    // gather fragments into raw[]: 16 contiguous lanes per fragment (64 B)
    for (int fb = 0; fb < NPART; fb += (CBS >> 4)) {
        int f = fb + (t >> 4);
        const unsigned* pp = packed + (size_t)f * epb + offs[f];
        int base = fbase[f];
        int len  = ((f + 1 < NPART) ? fbase[f + 1] : bsize) - base;
        for (int i = (t & 15); i < len; i += 16) {
            int p = base + i;
            if (p < CAP) raw[p] = pp[i];
        }
    }
    __syncthreads();
    // node-level count; cache records in registers for the scatter
    unsigned rr[CITER];
#pragma unroll
    for (int j = 0; j < CITER; ++j) {
        int i = j * CBS + t;
        rr[j] = 0xFFFFFFFFu;
        if (i < bsize) {
            rr[j] = raw[i];
            atomicAdd(&cnt[rr[j] >> 17], 1);
        }
    }
    __syncthreads();
    int myc = (t < NPB) ? cnt[t] : 0;
    __syncthreads();
    int cexcl = block_exscan<CBS / 64>(myc, t, wsum);
    if (t < NPB) {
        cur[t] = cexcl;                        // cursor for scatter
        int d = k * NPB + t;
        if (d < n) {
            int st = k * CAP + cexcl;
            seg[d] = make_int2(st, min(st + myc, (k + 1) * CAP));
            float r = rsqrtf((float)(myc + 1)); // +1 self-loop
            dis[d] = r;
            p1[d]  = x[d] * r;
        }
    }
    __syncthreads();
    // scatter into node-sorted order (from registers)
    unsigned* sb = sorted + (size_t)k * CAP;
#pragma unroll
    for (int j = 0; j < CITER; ++j)
        if (rr[j] != 0xFFFFFFFFu) {
            int pos = atomicAdd(&cur[rr[j] >> 17], 1);
            sb[pos] = rr[j];
        }
}

// ---- layer 1: atomic-free segment reduce + fused MLP -> p2 ----
__global__ __launch_bounds__(ABS) void k_agg1(
    const unsigned* __restrict__ sorted, const int2* __restrict__ seg,
    const float* __restrict__ dis, const float* __restrict__ p1,
    const float* __restrict__ W1, const float* __restrict__ b1,
    const float* __restrict__ W2, int n, float2* __restrict__ p2)
{
    int gid = blockIdx.x * ABS + threadIdx.x;
    int d = gid >> 3, lane = gid & (LPN - 1);
    if (d >= n) return;
    int2 se = seg[d];
    int s0 = se.x, e0 = se.y;
    float acc = 0.f;
    int i = s0 + lane;
    for (; i + 3 * LPN < e0; i += 4 * LPN) {   // 4 independent gathers in flight
        acc += p1[sorted[i] & 0x1FFFFu] + p1[sorted[i + LPN] & 0x1FFFFu]
             + p1[sorted[i + 2 * LPN] & 0x1FFFFu]
             + p1[sorted[i + 3 * LPN] & 0x1FFFFu];
    }
    for (; i < e0; i += LPN) acc += p1[sorted[i] & 0x1FFFFu];
    acc += __shfl_xor(acc, 1);
    acc += __shfl_xor(acc, 2);
    acc += __shfl_xor(acc, 4);
    if (lane == 0) {
        float r   = dis[d];
        float agg = r * (acc + p1[d]);          // + self-loop
        float c0 = 0.f, c1 = 0.f;
#pragma unroll
        for (int j = 0; j < 16; ++j) {
            float h = fmaxf(fmaf(agg, W1[j], b1[j]), 0.f);
            c0 = fmaf(h, W2[2 * j],     c0);
            c1 = fmaf(h, W2[2 * j + 1], c1);
        }
        p2[d] = make_float2(c0 * r, c1 * r);    // prescaled by dis[src]
    }
}

// ---- layer 2: atomic-free segment reduce + fused log-softmax -> out ----
__global__ __launch_bounds__(ABS) void k_agg2(
    const unsigned* __restrict__ sorted, const int2* __restrict__ seg,
    const float* __restrict__ dis, const float2* __restrict__ p2,
    const float* __restrict__ b2, int n, float2* __restrict__ out)
{
    int gid = blockIdx.x * ABS + threadIdx.x;
    int d = gid >> 3, lane = gid & (LPN - 1);
    if (d >= n) return;
    int2 se = seg[d];
    int s0 = se.x, e0 = se.y;
    float c0 = 0.f, c1 = 0.f;
    int i = s0 + lane;
    for (; i + 3 * LPN < e0; i += 4 * LPN) {   // 4 gathers in flight
        float2 v0 = p2[sorted[i]           & 0x1FFFFu];
        float2 v1 = p2[sorted[i + LPN]     & 0x1FFFFu];
        float2 v2 = p2[sorted[i + 2 * LPN] & 0x1FFFFu];
        float2 v3 = p2[sorted[i + 3 * LPN] & 0x1FFFFu];
        c0 += v0.x + v1.x + v2.x + v3.x;
        c1 += v0.y + v1.y + v2.y + v3.y;
    }
    for (; i < e0; i += LPN) {
        float2 v = p2[sorted[i] & 0x1FFFFu];
        c0 += v.x; c1 += v.y;
    }
    c0 += __shfl_xor(c0, 1); c0 += __shfl_xor(c0, 2); c0 += __shfl_xor(c0, 4);
    c1 += __shfl_xor(c1, 1); c1 += __shfl_xor(c1, 2); c1 += __shfl_xor(c1, 4);
    if (lane == 0) {
        float r = dis[d];
        float2 self = p2[d];
        float o0 = r * (c0 + self.x) + b2[0];
        float o1 = r * (c1 + self.y) + b2[1];
        float m  = fmaxf(o0, o1);
        float ls = m + logf(expf(o0 - m) + expf(o1 - m));
        out[d] = make_float2(o0 - ls, o1 - ls);
    }
}

extern "C" void kernel_launch(void* const* d_in, const int* in_sizes, int n_in,
                              void* d_out, int out_size, void* d_ws, size_t ws_size,
                              hipStream_t stream) {
    const float* x  = (const float*)d_in[0];
    const int*   ei = (const int*)d_in[1];     // int32 [2, E]
    const float* W1 = (const float*)d_in[2];
    const float* b1 = (const float*)d_in[3];
    const float* W2 = (const float*)d_in[4];
    const float* b2 = (const float*)d_in[5];

    const int n = in_sizes[0];                 // 100000
    const int E = in_sizes[1] / 2;             // 3200000
    const int* src = ei;
    const int* dst = ei + E;

    const int nbuck = (n + NPB - 1) >> NBSH;   // 391
    const int epb   = (E + NPART - 1) / NPART; // 6250

    char* ws = (char*)d_ws;
    size_t off = 0;
    auto take = [&](size_t bytes) { char* p = ws + off; off += (bytes + 7) & ~(size_t)7; return p; };
    int*      offT   = (int*)take((size_t)NPART * nbuck * 4);     // 0.8 MB
    unsigned* packed = (unsigned*)take((size_t)E * 4);            // 12.8 MB
    unsigned* sorted = (unsigned*)take((size_t)nbuck * CAP * 4);  // 15.2 MB
    int2*     seg    = (int2*)take((size_t)n * 8);
    float*    dis    = (float*)take((size_t)n * 4);
    float*    p1     = (float*)take((size_t)n * 4);
    float2*   p2     = (float2*)take((size_t)n * 8);

    const int gridAgg = ((size_t)n * LPN + ABS - 1) / ABS;        // 3125

    k_part<<<NPART, PBS, 0, stream>>>(src, dst, E, epb, nbuck, offT, packed);
    k_csr <<<nbuck, CBS, 0, stream>>>(packed, offT, x, E, epb, nbuck, n,
                                      sorted, seg, dis, p1);
    k_agg1<<<gridAgg, ABS, 0, stream>>>(sorted, seg, dis, p1,
                                        W1, b1, W2, n, p2);
    k_agg2<<<gridAgg, ABS, 0, stream>>>(sorted, seg, dis, p2,
                                        b2, n, (float2*)d_out);
}

// Round 18
// 76.083 us; speedup vs baseline: 1.1479x; 1.0008x over previous
//
#include <hip/hip_runtime.h>

// GCN 2-layer for MI355X — two-level counting sort to per-node CSR, then
// atomic-free register-reduction aggregation.
// r18: halve LDS atomics in both sort kernels. The count-phase
// atomicAdd's RETURN VALUE is a unique within-bucket rank; after the
// exclusive scan, scatter position = base[bkt] + rank (plain LDS read,
// no cursor atomic). k_part and k_csr each drop from 2 -> 1 LDS
// atomics/edge (r17 arithmetic: k_part was at ~1.8 cyc/atomic, i.e.
// LDS-atomic throughput bound).
//
// record: src (bits 0..16) | local_dst (bits 17..24), NPB=256

#define NPB    256
#define NBSH   8
#define NPART  512      // partition blocks
#define PBS    1024     // k_part threads
#define EPT    7        // edges/thread in k_part (epb=6250 <= 7168)
#define CAP    9728     // per-bucket capacity (mean 8184, sd ~90; +17 sd)
#define CBS    1024     // k_csr threads
#define CITER  10       // ceil(CAP/CBS)
#define ABS    256      // agg threads
#define LPN    8        // lanes per node in agg

// Block-wide exclusive scan via wave shuffles. NW = waves/block.
template <int NW>
__device__ __forceinline__ int block_exscan(int v, int t, int* wsum) {
    int lane = t & 63, wid = t >> 6;
    int inc = v;
#pragma unroll
    for (int off = 1; off < 64; off <<= 1) {
        int u = __shfl_up(inc, off);
        if (lane >= off) inc += u;
    }
    if (lane == 63) wsum[wid] = inc;
    __syncthreads();
    if (wid == 0) {
        int w = (lane < NW) ? wsum[lane] : 0;
#pragma unroll
        for (int off = 1; off < NW; off <<= 1) {
            int u = __shfl_up(w, off);
            if (lane >= off) w += u;
        }
        if (lane < NW) wsum[lane] = w;
    }
    __syncthreads();
    return inc - v + (wid ? wsum[wid - 1] : 0);
}

// ---- level 1: block-major bucket sort (rank from count atomic) ----
__global__ __launch_bounds__(PBS) void k_part(
    const int* __restrict__ src, const int* __restrict__ dst,
    int E, int epb, int nbuck,
    int* __restrict__ offT, unsigned* __restrict__ packed)
{
    __shared__ int s_scan[PBS];
    __shared__ unsigned stage[PBS * EPT];
    __shared__ int wsum[PBS / 64];
    const int b = blockIdx.x, t = threadIdx.x;
    const int lo = b * epb;
    int blockEdges = min(epb, E - lo); if (blockEdges < 0) blockEdges = 0;

    unsigned rec[EPT]; int bkt[EPT]; int rnk[EPT];
    s_scan[t] = 0;
    __syncthreads();
#pragma unroll
    for (int it = 0; it < EPT; ++it) {
        int idx = it * PBS + t;
        bkt[it] = -1; rec[it] = 0;
        if (idx < blockEdges) {
            int d = dst[lo + idx], s = src[lo + idx];
            rec[it] = (unsigned)s | ((unsigned)(d & (NPB - 1)) << 17);
            bkt[it] = d >> NBSH;
            rnk[it] = atomicAdd(&s_scan[bkt[it]], 1);   // count + rank
        }
    }
    __syncthreads();
    int v = s_scan[t];
    __syncthreads();
    int excl = block_exscan<PBS / 64>(v, t, wsum);
    s_scan[t] = excl;                          // per-bucket base
    if (t < nbuck) offT[(size_t)b * nbuck + t] = excl;
    __syncthreads();
#pragma unroll
    for (int it = 0; it < EPT; ++it)
        if (bkt[it] >= 0)
            stage[s_scan[bkt[it]] + rnk[it]] = rec[it];  // no atomic
    __syncthreads();
    for (int i = t; i < blockEdges; i += PBS)
        packed[(size_t)lo + i] = stage[i];
}

// ---- level 2: per-bucket node-level sort -> CSR + deg/dis/p1 fused ----
__global__ __launch_bounds__(CBS) void k_csr(
    const unsigned* __restrict__ packed, const int* __restrict__ offT,
    const float* __restrict__ x,
    int E, int epb, int nbuck, int n,
    unsigned* __restrict__ sorted, int2* __restrict__ seg,
    float* __restrict__ dis, float* __restrict__ p1)
{
    __shared__ unsigned raw[CAP];
    __shared__ int offs[NPART], fbase[NPART];
    __shared__ int cnt[NPB], cur[NPB];
    __shared__ int wsum[CBS / 64];
    __shared__ int s_bsize;
    const int k = blockIdx.x, t = threadIdx.x;

    int o = 0, myflen = 0;
    if (t < NPART) {
        o = offT[(size_t)t * nbuck + k];
        int e = (k + 1 < nbuck) ? offT[(size_t)t * nbuck + k + 1]
                                : max(0, min(epb, E - t * epb));
        myflen = e - o;
        offs[t] = o;
    }
    if (t < NPB) cnt[t] = 0;
    __syncthreads();
    int fexcl = block_exscan<CBS / 64>(myflen, t, wsum);
    if (t < NPART) fbase[t] = fexcl;
    if (t == NPART - 1) s_bsize = min(fexcl + myflen, CAP);
    __syncthreads();
    const int bsize = s_bsize;
    // gather fragments into raw[]: 16 contiguous lanes per fragment (64 B)
    for (int fb = 0; fb < NPART; fb += (CBS >> 4)) {
        int f = fb + (t >> 4);
        const unsigned* pp = packed + (size_t)f * epb + offs[f];
        int base = fbase[f];
        int len  = ((f + 1 < NPART) ? fbase[f + 1] : bsize) - base;
        for (int i = (t & 15); i < len; i += 16) {
            int p = base + i;
            if (p < CAP) raw[p] = pp[i];
        }
    }
    __syncthreads();
    // node-level count; the atomic's return is the within-node rank
    unsigned rr[CITER]; int rk[CITER];
#pragma unroll
    for (int j = 0; j < CITER; ++j) {
        int i = j * CBS + t;
        rr[j] = 0xFFFFFFFFu;
        if (i < bsize) {
            rr[j] = raw[i];
            rk[j] = atomicAdd(&cnt[rr[j] >> 17], 1);
        }
    }
    __syncthreads();
    int myc = (t < NPB) ? cnt[t] : 0;
    __syncthreads();
    int cexcl = block_exscan<CBS / 64>(myc, t, wsum);
    if (t < NPB) {
        cur[t] = cexcl;                        // per-node base
        int d = k * NPB + t;
        if (d < n) {
            int st = k * CAP + cexcl;
            seg[d] = make_int2(st, min(st + myc, (k + 1) * CAP));
            float r = rsqrtf((float)(myc + 1)); // +1 self-loop
            dis[d] = r;
            p1[d]  = x[d] * r;
        }
    }
    __syncthreads();
    // scatter into node-sorted order (base + rank, no atomic)
    unsigned* sb = sorted + (size_t)k * CAP;
#pragma unroll
    for (int j = 0; j < CITER; ++j)
        if (rr[j] != 0xFFFFFFFFu)
            sb[cur[rr[j] >> 17] + rk[j]] = rr[j];
}

// ---- layer 1: atomic-free segment reduce + fused MLP -> p2 ----
__global__ __launch_bounds__(ABS) void k_agg1(
    const unsigned* __restrict__ sorted, const int2* __restrict__ seg,
    const float* __restrict__ dis, const float* __restrict__ p1,
    const float* __restrict__ W1, const float* __restrict__ b1,
    const float* __restrict__ W2, int n, float2* __restrict__ p2)
{
    int gid = blockIdx.x * ABS + threadIdx.x;
    int d = gid >> 3, lane = gid & (LPN - 1);
    if (d >= n) return;
    int2 se = seg[d];
    int s0 = se.x, e0 = se.y;
    float acc = 0.f;
    int i = s0 + lane;
    for (; i + 3 * LPN < e0; i += 4 * LPN) {   // 4 independent gathers in flight
        acc += p1[sorted[i] & 0x1FFFFu] + p1[sorted[i + LPN] & 0x1FFFFu]
             + p1[sorted[i + 2 * LPN] & 0x1FFFFu]
             + p1[sorted[i + 3 * LPN] & 0x1FFFFu];
    }
    for (; i < e0; i += LPN) acc += p1[sorted[i] & 0x1FFFFu];
    acc += __shfl_xor(acc, 1);
    acc += __shfl_xor(acc, 2);
    acc += __shfl_xor(acc, 4);
    if (lane == 0) {
        float r   = dis[d];
        float agg = r * (acc + p1[d]);          // + self-loop
        float c0 = 0.f, c1 = 0.f;
#pragma unroll
        for (int j = 0; j < 16; ++j) {
            float h = fmaxf(fmaf(agg, W1[j], b1[j]), 0.f);
            c0 = fmaf(h, W2[2 * j],     c0);
            c1 = fmaf(h, W2[2 * j + 1], c1);
        }
        p2[d] = make_float2(c0 * r, c1 * r);    // prescaled by dis[src]
    }
}

// ---- layer 2: atomic-free segment reduce + fused log-softmax -> out ----
__global__ __launch_bounds__(ABS) void k_agg2(
    const unsigned* __restrict__ sorted, const int2* __restrict__ seg,
    const float* __restrict__ dis, const float2* __restrict__ p2,
    const float* __restrict__ b2, int n, float2* __restrict__ out)
{
    int gid = blockIdx.x * ABS + threadIdx.x;
    int d = gid >> 3, lane = gid & (LPN - 1);
    if (d >= n) return;
    int2 se = seg[d];
    int s0 = se.x, e0 = se.y;
    float c0 = 0.f, c1 = 0.f;
    int i = s0 + lane;
    for (; i + 3 * LPN < e0; i += 4 * LPN) {   // 4 gathers in flight
        float2 v0 = p2[sorted[i]           & 0x1FFFFu];
        float2 v1 = p2[sorted[i + LPN]     & 0x1FFFFu];
        float2 v2 = p2[sorted[i + 2 * LPN] & 0x1FFFFu];
        float2 v3 = p2[sorted[i + 3 * LPN] & 0x1FFFFu];
        c0 += v0.x + v1.x + v2.x + v3.x;
        c1 += v0.y + v1.y + v2.y + v3.y;
    }
    for (; i < e0; i += LPN) {
        float2 v = p2[sorted[i] & 0x1FFFFu];
        c0 += v.x; c1 += v.y;
    }
    c0 += __shfl_xor(c0, 1); c0 += __shfl_xor(c0, 2); c0 += __shfl_xor(c0, 4);
    c1 += __shfl_xor(c1, 1); c1 += __shfl_xor(c1, 2); c1 += __shfl_xor(c1, 4);
    if (lane == 0) {
        float r = dis[d];
        float2 self = p2[d];
        float o0 = r * (c0 + self.x) + b2[0];
        float o1 = r * (c1 + self.y) + b2[1];
        float m  = fmaxf(o0, o1);
        float ls = m + logf(expf(o0 - m) + expf(o1 - m));
        out[d] = make_float2(o0 - ls, o1 - ls);
    }
}

extern "C" void kernel_launch(void* const* d_in, const int* in_sizes, int n_in,
                              void* d_out, int out_size, void* d_ws, size_t ws_size,
                              hipStream_t stream) {
    const float* x  = (const float*)d_in[0];
    const int*   ei = (const int*)d_in[1];     // int32 [2, E]
    const float* W1 = (const float*)d_in[2];
    const float* b1 = (const float*)d_in[3];
    const float* W2 = (const float*)d_in[4];
    const float* b2 = (const float*)d_in[5];

    const int n = in_sizes[0];                 // 100000
    const int E = in_sizes[1] / 2;             // 3200000
    const int* src = ei;
    const int* dst = ei + E;

    const int nbuck = (n + NPB - 1) >> NBSH;   // 391
    const int epb   = (E + NPART - 1) / NPART; // 6250

    char* ws = (char*)d_ws;
    size_t off = 0;
    auto take = [&](size_t bytes) { char* p = ws + off; off += (bytes + 7) & ~(size_t)7; return p; };
    int*      offT   = (int*)take((size_t)NPART * nbuck * 4);     // 0.8 MB
    unsigned* packed = (unsigned*)take((size_t)E * 4);            // 12.8 MB
    unsigned* sorted = (unsigned*)take((size_t)nbuck * CAP * 4);  // 15.2 MB
    int2*     seg    = (int2*)take((size_t)n * 8);
    float*    dis    = (float*)take((size_t)n * 4);
    float*    p1     = (float*)take((size_t)n * 4);
    float2*   p2     = (float2*)take((size_t)n * 8);

    const int gridAgg = ((size_t)n * LPN + ABS - 1) / ABS;        // 3125

    k_part<<<NPART, PBS, 0, stream>>>(src, dst, E, epb, nbuck, offT, packed);
    k_csr <<<nbuck, CBS, 0, stream>>>(packed, offT, x, E, epb, nbuck, n,
                                      sorted, seg, dis, p1);
    k_agg1<<<gridAgg, ABS, 0, stream>>>(sorted, seg, dis, p1,
                                        W1, b1, W2, n, p2);
    k_agg2<<<gridAgg, ABS, 0, stream>>>(sorted, seg, dis, p2,
                                        b2, n, (float2*)d_out);
}